// Round 1
// baseline (92.215 us; speedup 1.0000x reference)
//
#include <hip/hip_runtime.h>
#include <hip/hip_bf16.h>

constexpr int N_PTS = 5000;
constexpr int CF    = 32;
constexpr int K_NMS = 64;
#define R2 0.01f

// ---------------- Kernel 1: score header + feature L2-normalize + xyz copy ----
__global__ __launch_bounds__(256) void score_feat_kernel(
    const float* __restrict__ xyz,       // [N,3]
    const float* __restrict__ feats,     // [C,N]
    const float* __restrict__ W1,        // [C,C]
    const float* __restrict__ b1,        // [C]
    const float* __restrict__ bn_gamma,  // [C]
    const float* __restrict__ bn_beta,   // [C]
    const float* __restrict__ bn_mean,   // [C]
    const float* __restrict__ bn_var,    // [C]
    const float* __restrict__ W2,        // [1,C]
    const float* __restrict__ b2,        // [1]
    float* __restrict__ out,             // [3N + N + N*C]
    float* __restrict__ scores_ws)       // [N] raw sigmoid scores
{
    __shared__ float sW1[CF * CF];
    __shared__ float sScale[CF], sB1[CF], sMean[CF], sBeta[CF], sW2[CF];
    __shared__ float sB2;
    const int t = threadIdx.x;
    for (int k = t; k < CF * CF; k += 256) sW1[k] = W1[k];
    if (t < CF) {
        sScale[t] = bn_gamma[t] / sqrtf(bn_var[t] + 1e-5f);
        sB1[t]    = b1[t];
        sMean[t]  = bn_mean[t];
        sBeta[t]  = bn_beta[t];
        sW2[t]    = W2[t];
    }
    if (t == 0) sB2 = b2[0];
    __syncthreads();

    const int i = blockIdx.x * 256 + t;
    if (i >= N_PTS) return;

    // feature column for point i
    float f[CF];
    #pragma unroll
    for (int c = 0; c < CF; ++c) f[c] = feats[c * N_PTS + i];

    // ---- score head: Conv1d(C,C,1) + BN(eval) + ReLU + Conv1d(C,1,1) + sigmoid
    float h2 = 0.f;
    #pragma unroll
    for (int c = 0; c < CF; ++c) {
        float acc = 0.f;
        #pragma unroll
        for (int k = 0; k < CF; ++k) acc = fmaf(sW1[c * CF + k], f[k], acc);
        float h1 = acc + sB1[c];
        float hb = (h1 - sMean[c]) * sScale[c] + sBeta[c];
        hb = fmaxf(hb, 0.f);
        h2 = fmaf(sW2[c], hb, h2);
    }
    const float xlin = h2 + sB2;
    const float s = 1.f / (1.f + expf(-xlin));
    scores_ws[i] = s;

    // ---- xyz passthrough
    out[3 * i + 0] = xyz[3 * i + 0];
    out[3 * i + 1] = xyz[3 * i + 1];
    out[3 * i + 2] = xyz[3 * i + 2];

    // ---- L2-normalized features, written [N,C] row-major
    float ssum = 0.f;
    #pragma unroll
    for (int c = 0; c < CF; ++c) ssum = fmaf(f[c], f[c], ssum);
    const float inv = 1.f / fmaxf(sqrtf(ssum), 1e-12f);
    float* fo = out + 4 * N_PTS + i * CF;
    #pragma unroll
    for (int c = 0; c < CF; ++c) fo[c] = f[c] * inv;
}

// ---------------- Kernel 2: ball-query (first-64 in index order) NMS ---------
__global__ __launch_bounds__(256) void nms_kernel(
    const float* __restrict__ xyz,     // [N,3]
    const float* __restrict__ scores,  // [N] raw scores
    float* __restrict__ out_scores)    // [N] suppressed scores
{
    __shared__ float sxyz[N_PTS * 3];   // 60000 B
    __shared__ float sscr[N_PTS];       // 20000 B
    const int t = threadIdx.x;
    for (int k = t; k < N_PTS * 3; k += 256) sxyz[k] = xyz[k];
    for (int k = t; k < N_PTS; k += 256) sscr[k] = scores[k];
    __syncthreads();

    const int wave = t >> 6;
    const int lane = t & 63;
    const unsigned long long lt_mask = (lane == 0) ? 0ull : (~0ull >> (64 - lane));

    // one wave per point; 256 blocks * 4 waves = 1024 points per round
    for (int p = blockIdx.x * 4 + wave; p < N_PTS; p += 256 * 4) {
        const float px = sxyz[3 * p + 0];
        const float py = sxyz[3 * p + 1];
        const float pz = sxyz[3 * p + 2];

        int cnt = 0;       // in-ball points seen so far (wave-uniform)
        float m = 0.f;     // running max over accepted neighbor scores
        for (int base = 0; base < N_PTS; base += 64) {
            const int j = base + lane;
            bool inball = false;
            if (j < N_PTS) {
                // exact numpy order: ((dx*dx + dy*dy) + dz*dz), no FMA contraction
                const float dx = __fsub_rn(px, sxyz[3 * j + 0]);
                const float dy = __fsub_rn(py, sxyz[3 * j + 1]);
                const float dz = __fsub_rn(pz, sxyz[3 * j + 2]);
                const float d2 = __fadd_rn(__fadd_rn(__fmul_rn(dx, dx),
                                                     __fmul_rn(dy, dy)),
                                           __fmul_rn(dz, dz));
                inball = d2 < R2;
            }
            const unsigned long long mask = __ballot(inball);
            const int prefix = __popcll(mask & lt_mask);
            if (inball && (cnt + prefix) < K_NMS) {
                m = fmaxf(m, sscr[j]);
            }
            cnt += __popcll(mask);
            if (cnt >= K_NMS) break;  // wave-uniform branch
        }
        // wave max-reduce
        #pragma unroll
        for (int off = 32; off >= 1; off >>= 1)
            m = fmaxf(m, __shfl_xor(m, off, 64));
        if (lane == 0) {
            const float s = sscr[p];
            out_scores[p] = (m == s) ? s : s * 1e-4f;
        }
    }
}

extern "C" void kernel_launch(void* const* d_in, const int* in_sizes, int n_in,
                              void* d_out, int out_size, void* d_ws, size_t ws_size,
                              hipStream_t stream) {
    const float* xyz      = (const float*)d_in[0];
    const float* feats    = (const float*)d_in[1];
    const float* W1       = (const float*)d_in[2];
    const float* b1       = (const float*)d_in[3];
    const float* bn_gamma = (const float*)d_in[4];
    const float* bn_beta  = (const float*)d_in[5];
    const float* bn_mean  = (const float*)d_in[6];
    const float* bn_var   = (const float*)d_in[7];
    const float* W2       = (const float*)d_in[8];
    const float* b2       = (const float*)d_in[9];
    float* out = (float*)d_out;
    float* scores_ws = (float*)d_ws;  // N floats

    const int grid1 = (N_PTS + 255) / 256;
    score_feat_kernel<<<grid1, 256, 0, stream>>>(
        xyz, feats, W1, b1, bn_gamma, bn_beta, bn_mean, bn_var, W2, b2,
        out, scores_ws);

    nms_kernel<<<256, 256, 0, stream>>>(xyz, scores_ws, out + 3 * N_PTS);
}

// Round 2
// 52.923 us; speedup vs baseline: 1.7424x; 1.7424x over previous
//
#include <hip/hip_runtime.h>
#include <hip/hip_bf16.h>

constexpr int N_PTS = 5000;
constexpr int CF    = 32;
constexpr int K_NMS = 64;
constexpr int S_SEG = 16;                             // candidate segments
constexpr int SEG   = (N_PTS + S_SEG - 1) / S_SEG;    // 313
constexpr int SEG_PAD = 320;
#define R2 0.01f

// ---------------- Kernel 1: score header + feature L2-normalize + xyz copy ----
__global__ __launch_bounds__(256) void score_feat_kernel(
    const float* __restrict__ xyz,       // [N,3]
    const float* __restrict__ feats,     // [C,N]
    const float* __restrict__ W1,        // [C,C]
    const float* __restrict__ b1,        // [C]
    const float* __restrict__ bn_gamma,  // [C]
    const float* __restrict__ bn_beta,   // [C]
    const float* __restrict__ bn_mean,   // [C]
    const float* __restrict__ bn_var,    // [C]
    const float* __restrict__ W2,        // [1,C]
    const float* __restrict__ b2,        // [1]
    float* __restrict__ out,             // [3N + N + N*C]
    float* __restrict__ scores_ws)       // [N] raw sigmoid scores
{
    __shared__ float sW1[CF * CF];
    __shared__ float sScale[CF], sB1[CF], sMean[CF], sBeta[CF], sW2[CF];
    __shared__ float sB2;
    const int t = threadIdx.x;
    for (int k = t; k < CF * CF; k += 256) sW1[k] = W1[k];
    if (t < CF) {
        sScale[t] = bn_gamma[t] / sqrtf(bn_var[t] + 1e-5f);
        sB1[t]    = b1[t];
        sMean[t]  = bn_mean[t];
        sBeta[t]  = bn_beta[t];
        sW2[t]    = W2[t];
    }
    if (t == 0) sB2 = b2[0];
    __syncthreads();

    const int i = blockIdx.x * 256 + t;
    if (i >= N_PTS) return;

    float f[CF];
    #pragma unroll
    for (int c = 0; c < CF; ++c) f[c] = feats[c * N_PTS + i];

    float h2 = 0.f;
    #pragma unroll
    for (int c = 0; c < CF; ++c) {
        float acc = 0.f;
        #pragma unroll
        for (int k = 0; k < CF; ++k) acc = fmaf(sW1[c * CF + k], f[k], acc);
        float h1 = acc + sB1[c];
        float hb = (h1 - sMean[c]) * sScale[c] + sBeta[c];
        hb = fmaxf(hb, 0.f);
        h2 = fmaf(sW2[c], hb, h2);
    }
    const float xlin = h2 + sB2;
    const float s = 1.f / (1.f + expf(-xlin));
    scores_ws[i] = s;

    out[3 * i + 0] = xyz[3 * i + 0];
    out[3 * i + 1] = xyz[3 * i + 1];
    out[3 * i + 2] = xyz[3 * i + 2];

    float ssum = 0.f;
    #pragma unroll
    for (int c = 0; c < CF; ++c) ssum = fmaf(f[c], f[c], ssum);
    const float inv = 1.f / fmaxf(sqrtf(ssum), 1e-12f);
    float* fo = out + 4 * N_PTS + i * CF;
    #pragma unroll
    for (int c = 0; c < CF; ++c) fo[c] = f[c] * inv;
}

// ---------------- NMS phase 1: per-(point, segment) in-ball count + set max --
// Thread-per-point; candidate loop is wave-uniform -> LDS broadcast reads.
__global__ __launch_bounds__(256) void nms_seg_kernel(
    const float* __restrict__ xyz,      // [N,3]
    const float* __restrict__ scores,   // [N]
    int*   __restrict__ cnt_ws,         // [S][N]
    float* __restrict__ max_ws)         // [S][N]
{
    __shared__ float sx[SEG_PAD], sy[SEG_PAD], sz[SEG_PAD], ss[SEG_PAD];
    const int s  = blockIdx.y;
    const int j0 = s * SEG;
    const int jn = min(SEG, N_PTS - j0);
    const int t  = threadIdx.x;
    for (int k = t; k < jn; k += 256) {
        const int j = j0 + k;
        sx[k] = xyz[3 * j + 0];
        sy[k] = xyz[3 * j + 1];
        sz[k] = xyz[3 * j + 2];
        ss[k] = scores[j];
    }
    __syncthreads();

    const int i = blockIdx.x * 256 + t;
    if (i >= N_PTS) return;
    const float px = xyz[3 * i + 0];
    const float py = xyz[3 * i + 1];
    const float pz = xyz[3 * i + 2];

    int cnt = 0;
    float m = 0.f;
    #pragma unroll 4
    for (int k = 0; k < jn; ++k) {
        // exact numpy order: ((dx*dx + dy*dy) + dz*dz), no FMA contraction
        const float dx = __fsub_rn(px, sx[k]);
        const float dy = __fsub_rn(py, sy[k]);
        const float dz = __fsub_rn(pz, sz[k]);
        const float d2 = __fadd_rn(__fadd_rn(__fmul_rn(dx, dx),
                                             __fmul_rn(dy, dy)),
                                   __fmul_rn(dz, dz));
        if (d2 < R2) { ++cnt; m = fmaxf(m, ss[k]); }
    }
    cnt_ws[s * N_PTS + i] = cnt;
    max_ws[s * N_PTS + i] = m;
}

// ---------------- NMS phase 2: combine segments; rare >64 exact fallback -----
__global__ __launch_bounds__(256) void nms_combine_kernel(
    const float* __restrict__ xyz,
    const float* __restrict__ scores,
    const int*   __restrict__ cnt_ws,
    const float* __restrict__ max_ws,
    float* __restrict__ out_scores)
{
    const int i = blockIdx.x * 256 + threadIdx.x;
    if (i >= N_PTS) return;
    int total = 0;
    float m = 0.f;
    #pragma unroll
    for (int s = 0; s < S_SEG; ++s) {
        total += cnt_ws[s * N_PTS + i];
        m = fmaxf(m, max_ws[s * N_PTS + i]);
    }
    if (total > K_NMS) {
        // exact first-64-in-index-order re-scan (essentially never taken)
        const float px = xyz[3 * i + 0];
        const float py = xyz[3 * i + 1];
        const float pz = xyz[3 * i + 2];
        m = 0.f;
        int taken = 0;
        for (int j = 0; j < N_PTS && taken < K_NMS; ++j) {
            const float dx = __fsub_rn(px, xyz[3 * j + 0]);
            const float dy = __fsub_rn(py, xyz[3 * j + 1]);
            const float dz = __fsub_rn(pz, xyz[3 * j + 2]);
            const float d2 = __fadd_rn(__fadd_rn(__fmul_rn(dx, dx),
                                                 __fmul_rn(dy, dy)),
                                       __fmul_rn(dz, dz));
            if (d2 < R2) { m = fmaxf(m, scores[j]); ++taken; }
        }
    }
    const float sc = scores[i];
    out_scores[i] = (m == sc) ? sc : sc * 1e-4f;
}

// ---------------- Fallback (small ws): original wave-per-point NMS -----------
__global__ __launch_bounds__(256) void nms_kernel(
    const float* __restrict__ xyz,
    const float* __restrict__ scores,
    float* __restrict__ out_scores)
{
    __shared__ float sxyz[N_PTS * 3];
    __shared__ float sscr[N_PTS];
    const int t = threadIdx.x;
    for (int k = t; k < N_PTS * 3; k += 256) sxyz[k] = xyz[k];
    for (int k = t; k < N_PTS; k += 256) sscr[k] = scores[k];
    __syncthreads();

    const int wave = t >> 6;
    const int lane = t & 63;
    const unsigned long long lt_mask = (lane == 0) ? 0ull : (~0ull >> (64 - lane));

    for (int p = blockIdx.x * 4 + wave; p < N_PTS; p += 256 * 4) {
        const float px = sxyz[3 * p + 0];
        const float py = sxyz[3 * p + 1];
        const float pz = sxyz[3 * p + 2];
        int cnt = 0;
        float m = 0.f;
        for (int base = 0; base < N_PTS; base += 64) {
            const int j = base + lane;
            bool inball = false;
            if (j < N_PTS) {
                const float dx = __fsub_rn(px, sxyz[3 * j + 0]);
                const float dy = __fsub_rn(py, sxyz[3 * j + 1]);
                const float dz = __fsub_rn(pz, sxyz[3 * j + 2]);
                const float d2 = __fadd_rn(__fadd_rn(__fmul_rn(dx, dx),
                                                     __fmul_rn(dy, dy)),
                                           __fmul_rn(dz, dz));
                inball = d2 < R2;
            }
            const unsigned long long mask = __ballot(inball);
            const int prefix = __popcll(mask & lt_mask);
            if (inball && (cnt + prefix) < K_NMS) m = fmaxf(m, sscr[j]);
            cnt += __popcll(mask);
            if (cnt >= K_NMS) break;
        }
        #pragma unroll
        for (int off = 32; off >= 1; off >>= 1)
            m = fmaxf(m, __shfl_xor(m, off, 64));
        if (lane == 0) {
            const float s = sscr[p];
            out_scores[p] = (m == s) ? s : s * 1e-4f;
        }
    }
}

extern "C" void kernel_launch(void* const* d_in, const int* in_sizes, int n_in,
                              void* d_out, int out_size, void* d_ws, size_t ws_size,
                              hipStream_t stream) {
    const float* xyz      = (const float*)d_in[0];
    const float* feats    = (const float*)d_in[1];
    const float* W1       = (const float*)d_in[2];
    const float* b1       = (const float*)d_in[3];
    const float* bn_gamma = (const float*)d_in[4];
    const float* bn_beta  = (const float*)d_in[5];
    const float* bn_mean  = (const float*)d_in[6];
    const float* bn_var   = (const float*)d_in[7];
    const float* W2       = (const float*)d_in[8];
    const float* b2       = (const float*)d_in[9];
    float* out = (float*)d_out;

    float* scores_ws = (float*)d_ws;                       // [N]
    int*   cnt_ws    = (int*)d_ws + N_PTS;                 // [S][N]
    float* max_ws    = (float*)d_ws + N_PTS + S_SEG * N_PTS; // [S][N]
    const size_t need = (size_t)(N_PTS + 2 * S_SEG * N_PTS) * sizeof(float);

    const int grid1 = (N_PTS + 255) / 256;                 // 20
    score_feat_kernel<<<grid1, 256, 0, stream>>>(
        xyz, feats, W1, b1, bn_gamma, bn_beta, bn_mean, bn_var, W2, b2,
        out, scores_ws);

    if (ws_size >= need) {
        dim3 g(grid1, S_SEG);
        nms_seg_kernel<<<g, 256, 0, stream>>>(xyz, scores_ws, cnt_ws, max_ws);
        nms_combine_kernel<<<grid1, 256, 0, stream>>>(
            xyz, scores_ws, cnt_ws, max_ws, out + 3 * N_PTS);
    } else {
        nms_kernel<<<256, 256, 0, stream>>>(xyz, scores_ws, out + 3 * N_PTS);
    }
}

// Round 3
// 37.683 us; speedup vs baseline: 2.4471x; 1.4045x over previous
//
#include <hip/hip_runtime.h>
#include <hip/hip_bf16.h>

constexpr int N_PTS = 5000;
constexpr int CF    = 32;
constexpr int K_NMS = 64;
constexpr int SEGS    = 32;                          // candidate segments
constexpr int SEGLEN  = (N_PTS + SEGS - 1) / SEGS;   // 157
constexpr int CHUNKS  = (SEGLEN + 63) / 64;          // 3
#define R2 0.01f

__device__ __forceinline__ float bcast_lane(float v, int kk) {
    return __uint_as_float(__builtin_amdgcn_readlane(__float_as_uint(v), kk));
}

// ---------------- Kernel 1: score header + feature L2-normalize + xyz copy ----
// UNCHANGED from round 1/2 — bit-matches the numpy reference (absmax 0.0).
__global__ __launch_bounds__(256) void score_feat_kernel(
    const float* __restrict__ xyz,       // [N,3]
    const float* __restrict__ feats,     // [C,N]
    const float* __restrict__ W1,        // [C,C]
    const float* __restrict__ b1,        // [C]
    const float* __restrict__ bn_gamma,  // [C]
    const float* __restrict__ bn_beta,   // [C]
    const float* __restrict__ bn_mean,   // [C]
    const float* __restrict__ bn_var,    // [C]
    const float* __restrict__ W2,        // [1,C]
    const float* __restrict__ b2,        // [1]
    float* __restrict__ out,             // [3N + N + N*C]
    float* __restrict__ scores_ws)       // [N] raw sigmoid scores
{
    __shared__ float sW1[CF * CF];
    __shared__ float sScale[CF], sB1[CF], sMean[CF], sBeta[CF], sW2[CF];
    __shared__ float sB2;
    const int t = threadIdx.x;
    for (int k = t; k < CF * CF; k += 256) sW1[k] = W1[k];
    if (t < CF) {
        sScale[t] = bn_gamma[t] / sqrtf(bn_var[t] + 1e-5f);
        sB1[t]    = b1[t];
        sMean[t]  = bn_mean[t];
        sBeta[t]  = bn_beta[t];
        sW2[t]    = W2[t];
    }
    if (t == 0) sB2 = b2[0];
    __syncthreads();

    const int i = blockIdx.x * 256 + t;
    if (i >= N_PTS) return;

    float f[CF];
    #pragma unroll
    for (int c = 0; c < CF; ++c) f[c] = feats[c * N_PTS + i];

    float h2 = 0.f;
    #pragma unroll
    for (int c = 0; c < CF; ++c) {
        float acc = 0.f;
        #pragma unroll
        for (int k = 0; k < CF; ++k) acc = fmaf(sW1[c * CF + k], f[k], acc);
        float h1 = acc + sB1[c];
        float hb = (h1 - sMean[c]) * sScale[c] + sBeta[c];
        hb = fmaxf(hb, 0.f);
        h2 = fmaf(sW2[c], hb, h2);
    }
    const float xlin = h2 + sB2;
    const float s = 1.f / (1.f + expf(-xlin));
    scores_ws[i] = s;

    out[3 * i + 0] = xyz[3 * i + 0];
    out[3 * i + 1] = xyz[3 * i + 1];
    out[3 * i + 2] = xyz[3 * i + 2];

    float ssum = 0.f;
    #pragma unroll
    for (int c = 0; c < CF; ++c) ssum = fmaf(f[c], f[c], ssum);
    const float inv = 1.f / fmaxf(sqrtf(ssum), 1e-12f);
    float* fo = out + 4 * N_PTS + i * CF;
    #pragma unroll
    for (int c = 0; c < CF; ++c) fo[c] = f[c] * inv;
}

// ---------------- NMS phase 1 (readlane): per-(point,seg) count + set max ----
// Candidates live in per-lane registers; broadcast via v_readlane (VALU pipe,
// SGPR result) -> zero DS traffic in the inner loop. P=2 points per thread.
__global__ __launch_bounds__(256) void nms_seg_rl_kernel(
    const float* __restrict__ xyz,      // [N,3]
    const float* __restrict__ scores,   // [N]
    uint2* __restrict__ ws2)            // [SEGS][N] (cnt, max-bits)
{
    const int lane = threadIdx.x & 63;
    const int wave = threadIdx.x >> 6;
    const int seg  = blockIdx.y * 4 + wave;          // [0,32)
    const int j0   = seg * SEGLEN;
    const int jn   = min(SEGLEN, N_PTS - j0);        // seg 31: 133
    const int p0   = blockIdx.x * 128 + lane;
    const int p1   = p0 + 64;

    float p0x, p0y, p0z, p1x, p1y, p1z;
    if (p0 < N_PTS) { p0x = xyz[3*p0]; p0y = xyz[3*p0+1]; p0z = xyz[3*p0+2]; }
    else            { p0x = p0y = p0z = 1e18f; }
    if (p1 < N_PTS) { p1x = xyz[3*p1]; p1y = xyz[3*p1+1]; p1z = xyz[3*p1+2]; }
    else            { p1x = p1y = p1z = 1e18f; }

    int   c0 = 0, c1 = 0;
    float m0 = 0.f, m1 = 0.f;

    #pragma unroll
    for (int c = 0; c < CHUNKS; ++c) {
        const int  slot = c * 64 + lane;
        const bool v    = slot < jn;
        const int  j    = v ? (j0 + slot) : 0;
        float lx = xyz[3*j+0];
        float ly = xyz[3*j+1];
        float lz = xyz[3*j+2];
        float ls = scores[j];
        if (!v) lx = 3e9f;   // (3e9)^2 = 9e18, never < R2

        #pragma unroll 4
        for (int kk = 0; kk < 64; ++kk) {
            const float cx = bcast_lane(lx, kk);
            const float cy = bcast_lane(ly, kk);
            const float cz = bcast_lane(lz, kk);
            const float cs = bcast_lane(ls, kk);
            {   // exact numpy order: ((dx*dx + dy*dy) + dz*dz), no FMA
                const float dx = __fsub_rn(p0x, cx);
                const float dy = __fsub_rn(p0y, cy);
                const float dz = __fsub_rn(p0z, cz);
                const float d2 = __fadd_rn(__fadd_rn(__fmul_rn(dx, dx),
                                                     __fmul_rn(dy, dy)),
                                           __fmul_rn(dz, dz));
                if (d2 < R2) { ++c0; m0 = fmaxf(m0, cs); }
            }
            {
                const float dx = __fsub_rn(p1x, cx);
                const float dy = __fsub_rn(p1y, cy);
                const float dz = __fsub_rn(p1z, cz);
                const float d2 = __fadd_rn(__fadd_rn(__fmul_rn(dx, dx),
                                                     __fmul_rn(dy, dy)),
                                           __fmul_rn(dz, dz));
                if (d2 < R2) { ++c1; m1 = fmaxf(m1, cs); }
            }
        }
    }
    if (p0 < N_PTS) ws2[seg * N_PTS + p0] = make_uint2((unsigned)c0, __float_as_uint(m0));
    if (p1 < N_PTS) ws2[seg * N_PTS + p1] = make_uint2((unsigned)c1, __float_as_uint(m1));
}

// ---------------- NMS phase 2: combine 32 segments; rare >64 exact fallback --
__global__ __launch_bounds__(256) void nms_combine32_kernel(
    const float* __restrict__ xyz,
    const float* __restrict__ scores,
    const uint2* __restrict__ ws2,
    float* __restrict__ out_scores)
{
    const int p = blockIdx.x * 256 + threadIdx.x;
    if (p >= N_PTS) return;
    int total = 0;
    float m = 0.f;
    #pragma unroll
    for (int s = 0; s < SEGS; ++s) {
        const uint2 v = ws2[s * N_PTS + p];
        total += (int)v.x;
        m = fmaxf(m, __uint_as_float(v.y));
    }
    if (total > K_NMS) {
        // exact first-64-in-index-order re-scan (essentially never taken)
        const float px = xyz[3*p], py = xyz[3*p+1], pz = xyz[3*p+2];
        m = 0.f;
        int taken = 0;
        for (int j = 0; j < N_PTS && taken < K_NMS; ++j) {
            const float dx = __fsub_rn(px, xyz[3*j+0]);
            const float dy = __fsub_rn(py, xyz[3*j+1]);
            const float dz = __fsub_rn(pz, xyz[3*j+2]);
            const float d2 = __fadd_rn(__fadd_rn(__fmul_rn(dx, dx),
                                                 __fmul_rn(dy, dy)),
                                       __fmul_rn(dz, dz));
            if (d2 < R2) { m = fmaxf(m, scores[j]); ++taken; }
        }
    }
    const float sc = scores[p];
    out_scores[p] = (m == sc) ? sc : sc * 1e-4f;
}

// ---------------- Fallback (small ws): wave-per-point NMS (round-1, exact) ---
__global__ __launch_bounds__(256) void nms_kernel(
    const float* __restrict__ xyz,
    const float* __restrict__ scores,
    float* __restrict__ out_scores)
{
    __shared__ float sxyz[N_PTS * 3];
    __shared__ float sscr[N_PTS];
    const int t = threadIdx.x;
    for (int k = t; k < N_PTS * 3; k += 256) sxyz[k] = xyz[k];
    for (int k = t; k < N_PTS; k += 256) sscr[k] = scores[k];
    __syncthreads();

    const int wave = t >> 6;
    const int lane = t & 63;
    const unsigned long long lt_mask = (lane == 0) ? 0ull : (~0ull >> (64 - lane));

    for (int p = blockIdx.x * 4 + wave; p < N_PTS; p += 256 * 4) {
        const float px = sxyz[3*p], py = sxyz[3*p+1], pz = sxyz[3*p+2];
        int cnt = 0;
        float m = 0.f;
        for (int base = 0; base < N_PTS; base += 64) {
            const int j = base + lane;
            bool inball = false;
            if (j < N_PTS) {
                const float dx = __fsub_rn(px, sxyz[3*j+0]);
                const float dy = __fsub_rn(py, sxyz[3*j+1]);
                const float dz = __fsub_rn(pz, sxyz[3*j+2]);
                const float d2 = __fadd_rn(__fadd_rn(__fmul_rn(dx, dx),
                                                     __fmul_rn(dy, dy)),
                                           __fmul_rn(dz, dz));
                inball = d2 < R2;
            }
            const unsigned long long mask = __ballot(inball);
            const int prefix = __popcll(mask & lt_mask);
            if (inball && (cnt + prefix) < K_NMS) m = fmaxf(m, sscr[j]);
            cnt += __popcll(mask);
            if (cnt >= K_NMS) break;
        }
        #pragma unroll
        for (int off = 32; off >= 1; off >>= 1)
            m = fmaxf(m, __shfl_xor(m, off, 64));
        if (lane == 0) {
            const float s = sscr[p];
            out_scores[p] = (m == s) ? s : s * 1e-4f;
        }
    }
}

extern "C" void kernel_launch(void* const* d_in, const int* in_sizes, int n_in,
                              void* d_out, int out_size, void* d_ws, size_t ws_size,
                              hipStream_t stream) {
    const float* xyz      = (const float*)d_in[0];
    const float* feats    = (const float*)d_in[1];
    const float* W1       = (const float*)d_in[2];
    const float* b1       = (const float*)d_in[3];
    const float* bn_gamma = (const float*)d_in[4];
    const float* bn_beta  = (const float*)d_in[5];
    const float* bn_mean  = (const float*)d_in[6];
    const float* bn_var   = (const float*)d_in[7];
    const float* W2       = (const float*)d_in[8];
    const float* b2       = (const float*)d_in[9];
    float* out = (float*)d_out;

    float* scores_ws = (float*)d_ws;                              // [N]
    uint2* ws2       = (uint2*)((char*)d_ws + N_PTS * sizeof(float)); // [SEGS][N]
    const size_t need = N_PTS * sizeof(float) + (size_t)SEGS * N_PTS * sizeof(uint2);

    const int grid1 = (N_PTS + 255) / 256;                        // 20
    score_feat_kernel<<<grid1, 256, 0, stream>>>(
        xyz, feats, W1, b1, bn_gamma, bn_beta, bn_mean, bn_var, W2, b2,
        out, scores_ws);

    if (ws_size >= need) {
        dim3 g((N_PTS + 127) / 128, SEGS / 4);                    // (40, 8)
        nms_seg_rl_kernel<<<g, 256, 0, stream>>>(xyz, scores_ws, ws2);
        nms_combine32_kernel<<<grid1, 256, 0, stream>>>(
            xyz, scores_ws, ws2, out + 3 * N_PTS);
    } else {
        nms_kernel<<<256, 256, 0, stream>>>(xyz, scores_ws, out + 3 * N_PTS);
    }
}